// Round 13
// baseline (120.483 us; speedup 1.0000x reference)
//
#include <hip/hip_runtime.h>

#define NNODES 50000
#define NEDGES 600000
#define NGRAPHS 64
#define NBKT 196                 // buckets: dst >> 8
#define EB 293                   // edge-chunk blocks (293*2048 >= 600000)
#define CHK 2048                 // edges per chunk
#define GEMM_BLKS 196

typedef __attribute__((ext_vector_type(8))) short short8;
typedef __attribute__((ext_vector_type(4))) float f32x4;

__device__ inline short f2bf(float f) {
    unsigned u = __float_as_uint(f);
    u = (u + 0x7fffu + ((u >> 16) & 1u)) >> 16;   // RNE
    return (short)u;
}
__device__ inline float bf_lo(unsigned w) { return __uint_as_float(w << 16); }
__device__ inline float bf_hi(unsigned w) { return __uint_as_float(w & 0xffff0000u); }
__device__ inline void fmabf8(const uint4 m, float n, float* a) {
    a[0] = fmaf(bf_lo(m.x), n, a[0]); a[1] = fmaf(bf_hi(m.x), n, a[1]);
    a[2] = fmaf(bf_lo(m.y), n, a[2]); a[3] = fmaf(bf_hi(m.y), n, a[3]);
    a[4] = fmaf(bf_lo(m.z), n, a[4]); a[5] = fmaf(bf_hi(m.z), n, a[5]);
    a[6] = fmaf(bf_lo(m.w), n, a[6]); a[7] = fmaf(bf_hi(m.w), n, a[7]);
}
__device__ inline void addbf8(const uint4 m, float* a) {
    a[0] += bf_lo(m.x); a[1] += bf_hi(m.x);
    a[2] += bf_lo(m.y); a[3] += bf_hi(m.y);
    a[4] += bf_lo(m.z); a[5] += bf_hi(m.z);
    a[6] += bf_lo(m.w); a[7] += bf_hi(m.w);
}

// ---------- init: W frag tables, zero out ----------
__device__ inline uint4 make_frag(const float* __restrict__ W, int M, int idx) {
    int lane = idx & 63, ks = (idx >> 6) & 3, cf = idx >> 8;
    int c = cf * 16 + (lane & 15);
    int k0 = ks * 32 + (lane >> 4) * 8;
    unsigned t[8];
    #pragma unroll
    for (int j = 0; j < 8; ++j)
        t[j] = (unsigned short)f2bf(W[(k0 + j) * M + c]);
    uint4 o;
    o.x = t[0] | (t[1] << 16);
    o.y = t[2] | (t[3] << 16);
    o.z = t[4] | (t[5] << 16);
    o.w = t[6] | (t[7] << 16);
    return o;
}

__global__ __launch_bounds__(256) void k_init0(const float* __restrict__ W1,
                                               const float* __restrict__ W2,
                                               unsigned short* __restrict__ Wf1,
                                               unsigned short* __restrict__ Wf2,
                                               float* __restrict__ dout) {
    int idx = blockIdx.x * 256 + threadIdx.x;     // 16 blocks = 4096 threads
    if (idx < NGRAPHS * 64) dout[idx] = 0.f;
    if (idx < 2048) {
        ((uint4*)Wf1)[idx] = make_frag(W1, 128, idx);
    } else if (idx < 3072) {
        ((uint4*)Wf2)[idx - 2048] = make_frag(W2, 64, idx - 2048);
    }
}

// ---------- mega1: blocks 0..195 = GEMM1 (Y = bf16(x@W1)); 196..488 = pass A bucket count ----------
__global__ __launch_bounds__(256) void k_mega1(const float* __restrict__ X,
                                               const unsigned short* __restrict__ Wf,
                                               unsigned short* __restrict__ Y,
                                               const int* __restrict__ ei,
                                               int* __restrict__ bh) {
    constexpr int CF = 8;
    constexpr int SLOTS = CF * 4 * 64;   // 2048
    __shared__ uint4 Bl[SLOTS];
    __shared__ int hist[NBKT];
    const int tid = threadIdx.x;

    if (blockIdx.x >= GEMM_BLKS) {
        // pass A: LDS histogram of dst buckets for this edge chunk (int4 reads)
        int eb = blockIdx.x - GEMM_BLKS;
        for (int i = tid; i < NBKT; i += 256) hist[i] = 0;
        __syncthreads();
        int e0 = eb * CHK;
        int e1 = min(e0 + CHK, NEDGES);
        int n4 = (e1 - e0) >> 2;
        const int4* dp = (const int4*)(ei + NEDGES + e0);
        for (int i = tid; i < n4; i += 256) {
            int4 d = dp[i];
            atomicAdd(&hist[d.x >> 8], 1);
            atomicAdd(&hist[d.y >> 8], 1);
            atomicAdd(&hist[d.z >> 8], 1);
            atomicAdd(&hist[d.w >> 8], 1);
        }
        __syncthreads();
        for (int i = tid; i < NBKT; i += 256) bh[i * EB + eb] = hist[i];
        return;
    }

    for (int i = tid; i < SLOTS; i += 256) Bl[i] = ((const uint4*)Wf)[i];
    __syncthreads();

    const short8* Bs8 = (const short8*)Bl;
    const int lane = tid & 63;
    const int wave = tid >> 6;
    const int qr = lane >> 4;
    const int cl = lane & 15;
    const int wid = blockIdx.x * 4 + wave;
    const int ngroups = (NNODES + 63) / 64;   // 782
    if (wid >= ngroups) return;

    const int base = wid * 64;
    short8 a[4][4];
    #pragma unroll
    for (int r = 0; r < 4; ++r) {
        int arow = base + r * 16 + cl;
        bool ok = arow < NNODES;
        #pragma unroll
        for (int ks = 0; ks < 4; ++ks) {
            short8 v = (short8)0;
            if (ok) {
                const float* xp = X + (long)arow * 128 + ks * 32 + qr * 8;
                float4 x0 = *reinterpret_cast<const float4*>(xp);
                float4 x1 = *reinterpret_cast<const float4*>(xp + 4);
                v[0] = f2bf(x0.x); v[1] = f2bf(x0.y); v[2] = f2bf(x0.z); v[3] = f2bf(x0.w);
                v[4] = f2bf(x1.x); v[5] = f2bf(x1.y); v[6] = f2bf(x1.z); v[7] = f2bf(x1.w);
            }
            a[r][ks] = v;
        }
    }
    f32x4 acc[4][CF];
    #pragma unroll
    for (int r = 0; r < 4; ++r)
        #pragma unroll
        for (int cf = 0; cf < CF; ++cf)
            acc[r][cf] = (f32x4){0.f, 0.f, 0.f, 0.f};
    #pragma unroll
    for (int cf = 0; cf < CF; ++cf)
        #pragma unroll
        for (int ks = 0; ks < 4; ++ks) {
            short8 b = Bs8[(cf * 4 + ks) * 64 + lane];
            #pragma unroll
            for (int r = 0; r < 4; ++r)
                acc[r][cf] = __builtin_amdgcn_mfma_f32_16x16x32_bf16(a[r][ks], b, acc[r][cf], 0, 0, 0);
        }
    #pragma unroll
    for (int r = 0; r < 4; ++r) {
        int row0 = base + r * 16 + qr * 4;
        #pragma unroll
        for (int i = 0; i < 4; ++i) {
            int row = row0 + i;
            if (row < NNODES) {
                #pragma unroll
                for (int cf = 0; cf < CF; ++cf)
                    Y[(long)row * 128 + cf * 16 + cl] = (unsigned short)f2bf(acc[r][cf][i]);
            }
        }
    }
}

// ---------- scanA1: per-bucket exclusive scan of its 293-chunk row; emit bucket total ----------
__global__ __launch_bounds__(512) void k_scanA1(int* __restrict__ bh,
                                                int* __restrict__ bt) {
    __shared__ int s[512];
    int b = blockIdx.x;
    int t = threadIdx.x;
    int v = (t < EB) ? bh[b * EB + t] : 0;
    s[t] = v;
    __syncthreads();
    for (int off = 1; off < 512; off <<= 1) {
        int u = (t >= off) ? s[t - off] : 0;
        __syncthreads();
        s[t] += u;
        __syncthreads();
    }
    if (t < EB) bh[b * EB + t] = s[t] - v;    // exclusive within row
    if (t == EB - 1) bt[b] = s[t];            // row total (unscanned)
}

// ---------- pass A2: partition edges into dst-buckets (local bt scan, LDS cursors) ----------
__global__ __launch_bounds__(256) void k_passA2(const int* __restrict__ ei,
                                                const int* __restrict__ bh,
                                                const int* __restrict__ bt,
                                                int2* __restrict__ parted) {
    __shared__ int sc[256];
    __shared__ int cur[NBKT];
    int eb = blockIdx.x;
    int t = threadIdx.x;
    int v = (t < NBKT) ? bt[t] : 0;
    sc[t] = v;
    __syncthreads();
    for (int off = 1; off < 256; off <<= 1) {
        int u = (t >= off) ? sc[t - off] : 0;
        __syncthreads();
        sc[t] += u;
        __syncthreads();
    }
    if (t < NBKT) cur[t] = (sc[t] - v) + bh[t * EB + eb];
    __syncthreads();
    int e0 = eb * CHK;
    int e1 = min(e0 + CHK, NEDGES);
    int n4 = (e1 - e0) >> 2;
    const int4* sp = (const int4*)(ei + e0);
    const int4* dp = (const int4*)(ei + NEDGES + e0);
    for (int i = t; i < n4; i += 256) {
        int4 sv = sp[i];
        int4 dv = dp[i];
        int p0 = atomicAdd(&cur[dv.x >> 8], 1); parted[p0] = make_int2(sv.x, dv.x);
        int p1 = atomicAdd(&cur[dv.y >> 8], 1); parted[p1] = make_int2(sv.y, dv.y);
        int p2 = atomicAdd(&cur[dv.z >> 8], 1); parted[p2] = make_int2(sv.z, dv.z);
        int p3 = atomicAdd(&cur[dv.w >> 8], 1); parted[p3] = make_int2(sv.w, dv.w);
    }
}

// ---------- pass B: per-bucket count/scan/scatter -> rp, csr_src, dinv (local bt scan) ----------
__global__ __launch_bounds__(256) void k_passB(const int* __restrict__ bt,
                                               const int2* __restrict__ parted,
                                               int* __restrict__ rp,
                                               int* __restrict__ csr,
                                               float* __restrict__ dinv) {
    __shared__ int cnt2[256], cur[256], sc[256];
    int b = blockIdx.x;
    int t = threadIdx.x;
    int v = (t < NBKT) ? bt[t] : 0;
    sc[t] = v;
    __syncthreads();
    for (int o = 1; o < 256; o <<= 1) {
        int u = (t >= o) ? sc[t - o] : 0;
        __syncthreads();
        sc[t] += u;
        __syncthreads();
    }
    __shared__ int lo_sh, hi_sh;
    if (t == b) { lo_sh = sc[t] - v; hi_sh = sc[t]; }
    __syncthreads();
    int lo = lo_sh, hi = hi_sh;
    cnt2[t] = 0;
    __syncthreads();
    for (int i = lo + t; i < hi; i += 256)
        atomicAdd(&cnt2[parted[i].y & 255], 1);
    __syncthreads();
    sc[t] = cnt2[t];
    __syncthreads();
    for (int o = 1; o < 256; o <<= 1) {
        int u = (t >= o) ? sc[t - o] : 0;
        __syncthreads();
        sc[t] += u;
        __syncthreads();
    }
    int excl = sc[t] - cnt2[t];
    cur[t] = excl;
    int vtx = b * 256 + t;
    if (vtx < NNODES) {
        rp[vtx] = lo + excl;
        dinv[vtx] = rsqrtf((float)cnt2[t] + 1.0f);
    } else if (vtx == NNODES) {
        rp[vtx] = lo + excl;   // = NEDGES (all higher bins empty)
    }
    __syncthreads();
    for (int i = lo + t; i < hi; i += 256) {
        int2 e = parted[i];
        int pos = lo + atomicAdd(&cur[e.y & 255], 1);
        csr[pos] = e.x;
    }
}

// ---------- fused: gather layer-1 (per-edge dinv[src], relu+bias) -> LDS -> @W2 ----------
__global__ __launch_bounds__(256) void k_gather_gemm(const int* __restrict__ rp,
                                                     const int* __restrict__ csr_src,
                                                     const float* __restrict__ dinv,
                                                     const unsigned short* __restrict__ Hs,
                                                     const float* __restrict__ b1,
                                                     const unsigned short* __restrict__ Wf2,
                                                     unsigned short* __restrict__ Y) {
    __shared__ unsigned short h1[64 * 128];    // 16 KB, XOR-swizzled rows
    const int tid = threadIdx.x;
    const int lane = tid & 63;
    const int wave = tid >> 6;

    const int grp = lane >> 4;
    const int ln = lane & 15;
    const int c8 = ln * 8;
    const int base = blockIdx.x * 64;
    const uint4* Hp = (const uint4*)Hs;
    float4 bv0 = *reinterpret_cast<const float4*>(b1 + c8);
    float4 bv1 = *reinterpret_cast<const float4*>(b1 + c8 + 4);
    float bb[8] = {bv0.x, bv0.y, bv0.z, bv0.w, bv1.x, bv1.y, bv1.z, bv1.w};

    #pragma unroll
    for (int p = 0; p < 4; ++p) {
        int vloc = wave * 16 + p * 4 + grp;
        int v = base + vloc;
        uint4 o = {0u, 0u, 0u, 0u};
        if (v < NNODES) {
            float a[8] = {0, 0, 0, 0, 0, 0, 0, 0};
            float dd = dinv[v];
            fmabf8(Hp[((long)v * 128 + c8) >> 3], dd, a);   // self * dinv[v]
            int lo = rp[v], hi = rp[v + 1];
            int i = lo;
            for (; i + 4 <= hi; i += 4) {
                int s0 = csr_src[i], s1 = csr_src[i + 1];
                int s2 = csr_src[i + 2], s3 = csr_src[i + 3];
                float n0 = dinv[s0], n1 = dinv[s1], n2 = dinv[s2], n3 = dinv[s3];
                uint4 m0 = Hp[((long)s0 * 128 + c8) >> 3];
                uint4 m1 = Hp[((long)s1 * 128 + c8) >> 3];
                uint4 m2 = Hp[((long)s2 * 128 + c8) >> 3];
                uint4 m3 = Hp[((long)s3 * 128 + c8) >> 3];
                fmabf8(m0, n0, a); fmabf8(m1, n1, a);
                fmabf8(m2, n2, a); fmabf8(m3, n3, a);
            }
            for (; i < hi; ++i) {
                int s = csr_src[i];
                fmabf8(Hp[((long)s * 128 + c8) >> 3], dinv[s], a);
            }
            unsigned t8[8];
            #pragma unroll
            for (int j = 0; j < 8; ++j) {
                float y = fmaxf(fmaf(a[j], dd, bb[j]), 0.f);
                t8[j] = (unsigned short)f2bf(y);
            }
            o.x = t8[0] | (t8[1] << 16);
            o.y = t8[2] | (t8[3] << 16);
            o.z = t8[4] | (t8[5] << 16);
            o.w = t8[6] | (t8[7] << 16);
        }
        int byte = (vloc * 256 + c8 * 2) ^ ((vloc & 7) << 4);
        *reinterpret_cast<uint4*>((char*)h1 + byte) = o;
    }
    __syncthreads();

    // Phase B: rows wave*16..+15 ; A-frag: row=wave*16+cl, ch=ks*32+qr*8 ; B from global
    const int qr = lane >> 4;
    const int cl = lane & 15;
    const int arow = wave * 16 + cl;
    short8 afr[4];
    #pragma unroll
    for (int ks = 0; ks < 4; ++ks) {
        int byte = (arow * 256 + (ks * 32 + qr * 8) * 2) ^ ((arow & 7) << 4);
        afr[ks] = *reinterpret_cast<const short8*>((const char*)h1 + byte);
    }
    const short8* Bs8 = (const short8*)Wf2;
    f32x4 acc[4];
    #pragma unroll
    for (int cf = 0; cf < 4; ++cf) acc[cf] = (f32x4){0.f, 0.f, 0.f, 0.f};
    #pragma unroll
    for (int cf = 0; cf < 4; ++cf)
        #pragma unroll
        for (int ks = 0; ks < 4; ++ks)
            acc[cf] = __builtin_amdgcn_mfma_f32_16x16x32_bf16(afr[ks], Bs8[(cf * 4 + ks) * 64 + lane], acc[cf], 0, 0, 0);
    #pragma unroll
    for (int i = 0; i < 4; ++i) {
        int row = base + wave * 16 + qr * 4 + i;
        if (row < NNODES) {
            float dv = dinv[row];
            #pragma unroll
            for (int cf = 0; cf < 4; ++cf)
                Y[(long)row * 64 + cf * 16 + cl] = (unsigned short)f2bf(acc[cf][i] * dv);
        }
    }
}

// ---------- fused gather layer 2 + pool ----------
// 196 blocks x 256 nodes; 8 lanes/node, 8 passes. Per-thread local accum per graph,
// flush on graph change -> LDS [64][64] f32 (LDS atomics, rare), then block -> global.
__global__ __launch_bounds__(256) void k_gather2_pool(const int* __restrict__ rp,
                                                      const int* __restrict__ csr_src,
                                                      const float* __restrict__ dinv,
                                                      const unsigned short* __restrict__ Hs,
                                                      const float* __restrict__ bias,
                                                      const int* __restrict__ batch,
                                                      float* __restrict__ out) {
    __shared__ float acc_sh[NGRAPHS * 64];   // 16 KB
    const int tid = threadIdx.x;
    for (int i = tid; i < NGRAPHS * 64; i += 256) acc_sh[i] = 0.f;
    __syncthreads();

    const int lane = tid & 7;
    const int grp = tid >> 3;
    const int c8 = lane * 8;
    const int base = blockIdx.x * 256;
    const uint4* Hp = (const uint4*)Hs;
    float4 bv0 = *reinterpret_cast<const float4*>(bias + c8);
    float4 bv1 = *reinterpret_cast<const float4*>(bias + c8 + 4);
    float bb[8] = {bv0.x, bv0.y, bv0.z, bv0.w, bv1.x, bv1.y, bv1.z, bv1.w};

    float loc[8] = {0, 0, 0, 0, 0, 0, 0, 0};
    int curg = -1;
    for (int p = 0; p < 8; ++p) {
        int v = base + p * 32 + grp;
        if (v >= NNODES) break;
        int g = batch[v];
        if (g != curg) {
            if (curg >= 0) {
                #pragma unroll
                for (int j = 0; j < 8; ++j)
                    atomicAdd(&acc_sh[curg * 64 + c8 + j], loc[j]);
            }
            curg = g;
            #pragma unroll
            for (int j = 0; j < 8; ++j) loc[j] = 0.f;
        }
        float dd = dinv[v];
        float a[8] = {0, 0, 0, 0, 0, 0, 0, 0};
        addbf8(Hp[((long)v * 64 + c8) >> 3], a);
        int lo = rp[v], hi = rp[v + 1];
        int i = lo;
        for (; i + 4 <= hi; i += 4) {
            int s0 = csr_src[i], s1 = csr_src[i + 1];
            int s2 = csr_src[i + 2], s3 = csr_src[i + 3];
            uint4 m0 = Hp[((long)s0 * 64 + c8) >> 3];
            uint4 m1 = Hp[((long)s1 * 64 + c8) >> 3];
            uint4 m2 = Hp[((long)s2 * 64 + c8) >> 3];
            uint4 m3 = Hp[((long)s3 * 64 + c8) >> 3];
            addbf8(m0, a); addbf8(m1, a); addbf8(m2, a); addbf8(m3, a);
        }
        for (; i < hi; ++i)
            addbf8(Hp[((long)csr_src[i] * 64 + c8) >> 3], a);
        #pragma unroll
        for (int j = 0; j < 8; ++j)
            loc[j] += fmaf(a[j], dd, bb[j]);
    }
    if (curg >= 0) {
        #pragma unroll
        for (int j = 0; j < 8; ++j)
            atomicAdd(&acc_sh[curg * 64 + c8 + j], loc[j]);
    }
    __syncthreads();

    // block-level flush: graphs [g0..g1] only
    int g0 = batch[min(base, NNODES - 1)];
    int g1 = batch[min(base + 255, NNODES - 1)];
    int slots = (g1 - g0 + 1) * 64;
    for (int i = tid; i < slots; i += 256) {
        float v = acc_sh[g0 * 64 + i];
        if (v != 0.f) atomicAdd(&out[g0 * 64 + i], v);
    }
}

// ---------- launch ----------
extern "C" void kernel_launch(void* const* d_in, const int* in_sizes, int n_in,
                              void* d_out, int out_size, void* d_ws, size_t ws_size,
                              hipStream_t stream) {
    const float* x   = (const float*)d_in[0];
    const int* ei    = (const int*)d_in[1];
    const int* batch = (const int*)d_in[2];
    const float* W1  = (const float*)d_in[3];
    const float* b1  = (const float*)d_in[4];
    const float* W2  = (const float*)d_in[5];
    const float* b2  = (const float*)d_in[6];
    float* out = (float*)d_out;

    char* ws = (char*)d_ws;
    float* dinv = (float*)ws;                                   // 200 KB
    int*   rp   = (int*)(ws + (256 << 10));                     // 50001 ints
    int*   bh   = (int*)(ws + (512 << 10));                     // 57428 ints (230 KB)
    int*   bt   = (int*)(ws + (768 << 10));                     // 196 ints
    int*   csr  = (int*)(ws + (1u << 20));                      // 2.4 MB
    unsigned short* Wf1 = (unsigned short*)(ws + (3584u << 10));              // 32 KB
    unsigned short* Wf2 = (unsigned short*)(ws + (3584u << 10) + (32 << 10)); // 16 KB
    unsigned short* bufA = (unsigned short*)(ws + (4u << 20));                // 12.8 MB
    unsigned short* bufB = (unsigned short*)(ws + (4u << 20) + (size_t)NNODES * 128 * 2); // 6.4 MB
    int2* parted = (int2*)bufB;   // 4.8 MB; liveness disjoint from bufB (A2/B vs gg/g2)

    // init (build W frags, zero out)
    k_init0<<<16, 256, 0, stream>>>(W1, W2, Wf1, Wf2, out);

    // mega1: GEMM1 (blocks 0..195) || pass A bucket histogram (blocks 196..488)
    k_mega1<<<GEMM_BLKS + EB, 256, 0, stream>>>(x, Wf1, bufA, ei, bh);

    // per-bucket chunk scan (emits unscanned bucket totals)
    k_scanA1<<<NBKT, 512, 0, stream>>>(bh, bt);

    // partition edges by dst bucket; then per-bucket CSR build (rp, csr, dinv)
    k_passA2<<<EB, 256, 0, stream>>>(ei, bh, bt, parted);
    k_passB<<<NBKT, 256, 0, stream>>>(bt, parted, rp, csr, dinv);

    // fused gather1(+bias+relu, per-edge dinv[src]) -> @W2 -> Hs2
    k_gather_gemm<<<(NNODES + 63) / 64, 256, 0, stream>>>(rp, csr, dinv, bufA, b1, Wf2, bufB);

    // fused gather2 (+bias) + global_add_pool -> out
    k_gather2_pool<<<(NNODES + 255) / 256, 256, 0, stream>>>(rp, csr, dinv, bufB, b2, batch, out);
}

// Round 14
// 97.854 us; speedup vs baseline: 1.2313x; 1.2313x over previous
//
#include <hip/hip_runtime.h>

#define NNODES 50000
#define NEDGES 600000
#define NGRAPHS 64
#define NBKT 196                 // buckets: dst >> 8
#define EB 293                   // edge-chunk blocks (293*2048 >= 600000)
#define CHK 2048                 // edges per chunk
#define GEMM_BLKS 196

typedef __attribute__((ext_vector_type(8))) short short8;
typedef __attribute__((ext_vector_type(4))) float f32x4;

__device__ inline short f2bf(float f) {
    unsigned u = __float_as_uint(f);
    u = (u + 0x7fffu + ((u >> 16) & 1u)) >> 16;   // RNE
    return (short)u;
}
__device__ inline float bf2f(unsigned short s) {
    return __uint_as_float(((unsigned)s) << 16);
}
__device__ inline float bf_lo(unsigned w) { return __uint_as_float(w << 16); }
__device__ inline float bf_hi(unsigned w) { return __uint_as_float(w & 0xffff0000u); }
__device__ inline void fmabf8(const uint4 m, float n, float* a) {
    a[0] = fmaf(bf_lo(m.x), n, a[0]); a[1] = fmaf(bf_hi(m.x), n, a[1]);
    a[2] = fmaf(bf_lo(m.y), n, a[2]); a[3] = fmaf(bf_hi(m.y), n, a[3]);
    a[4] = fmaf(bf_lo(m.z), n, a[4]); a[5] = fmaf(bf_hi(m.z), n, a[5]);
    a[6] = fmaf(bf_lo(m.w), n, a[6]); a[7] = fmaf(bf_hi(m.w), n, a[7]);
}
__device__ inline void addbf8(const uint4 m, float* a) {
    a[0] += bf_lo(m.x); a[1] += bf_hi(m.x);
    a[2] += bf_lo(m.y); a[3] += bf_hi(m.y);
    a[4] += bf_lo(m.z); a[5] += bf_hi(m.z);
    a[6] += bf_lo(m.w); a[7] += bf_hi(m.w);
}

// ---------- init: W frag tables, zero out ----------
__device__ inline uint4 make_frag(const float* __restrict__ W, int M, int idx) {
    int lane = idx & 63, ks = (idx >> 6) & 3, cf = idx >> 8;
    int c = cf * 16 + (lane & 15);
    int k0 = ks * 32 + (lane >> 4) * 8;
    unsigned t[8];
    #pragma unroll
    for (int j = 0; j < 8; ++j)
        t[j] = (unsigned short)f2bf(W[(k0 + j) * M + c]);
    uint4 o;
    o.x = t[0] | (t[1] << 16);
    o.y = t[2] | (t[3] << 16);
    o.z = t[4] | (t[5] << 16);
    o.w = t[6] | (t[7] << 16);
    return o;
}

__global__ __launch_bounds__(256) void k_init0(const float* __restrict__ W1,
                                               const float* __restrict__ W2,
                                               unsigned short* __restrict__ Wf1,
                                               unsigned short* __restrict__ Wf2,
                                               float* __restrict__ dout) {
    int idx = blockIdx.x * 256 + threadIdx.x;     // 16 blocks = 4096 threads
    if (idx < NGRAPHS * 64) dout[idx] = 0.f;
    if (idx < 2048) {
        ((uint4*)Wf1)[idx] = make_frag(W1, 128, idx);
    } else if (idx < 3072) {
        ((uint4*)Wf2)[idx - 2048] = make_frag(W2, 64, idx - 2048);
    }
}

// ---------- mega1: blocks 0..195 = GEMM1 (Y = bf16(x@W1)); 196..488 = pass A bucket count ----------
__global__ __launch_bounds__(256) void k_mega1(const float* __restrict__ X,
                                               const unsigned short* __restrict__ Wf,
                                               unsigned short* __restrict__ Y,
                                               const int* __restrict__ ei,
                                               int* __restrict__ bh) {
    constexpr int CF = 8;
    constexpr int SLOTS = CF * 4 * 64;   // 2048
    __shared__ uint4 Bl[SLOTS];
    __shared__ int hist[NBKT];
    const int tid = threadIdx.x;

    if (blockIdx.x >= GEMM_BLKS) {
        // pass A: LDS histogram of dst buckets for this edge chunk (int4 reads)
        int eb = blockIdx.x - GEMM_BLKS;
        for (int i = tid; i < NBKT; i += 256) hist[i] = 0;
        __syncthreads();
        int e0 = eb * CHK;
        int e1 = min(e0 + CHK, NEDGES);
        int n4 = (e1 - e0) >> 2;
        const int4* dp = (const int4*)(ei + NEDGES + e0);
        for (int i = tid; i < n4; i += 256) {
            int4 d = dp[i];
            atomicAdd(&hist[d.x >> 8], 1);
            atomicAdd(&hist[d.y >> 8], 1);
            atomicAdd(&hist[d.z >> 8], 1);
            atomicAdd(&hist[d.w >> 8], 1);
        }
        __syncthreads();
        for (int i = tid; i < NBKT; i += 256) bh[i * EB + eb] = hist[i];
        return;
    }

    for (int i = tid; i < SLOTS; i += 256) Bl[i] = ((const uint4*)Wf)[i];
    __syncthreads();

    const short8* Bs8 = (const short8*)Bl;
    const int lane = tid & 63;
    const int wave = tid >> 6;
    const int qr = lane >> 4;
    const int cl = lane & 15;
    const int wid = blockIdx.x * 4 + wave;
    const int ngroups = (NNODES + 63) / 64;   // 782
    if (wid >= ngroups) return;

    const int base = wid * 64;
    short8 a[4][4];
    #pragma unroll
    for (int r = 0; r < 4; ++r) {
        int arow = base + r * 16 + cl;
        bool ok = arow < NNODES;
        #pragma unroll
        for (int ks = 0; ks < 4; ++ks) {
            short8 v = (short8)0;
            if (ok) {
                const float* xp = X + (long)arow * 128 + ks * 32 + qr * 8;
                float4 x0 = *reinterpret_cast<const float4*>(xp);
                float4 x1 = *reinterpret_cast<const float4*>(xp + 4);
                v[0] = f2bf(x0.x); v[1] = f2bf(x0.y); v[2] = f2bf(x0.z); v[3] = f2bf(x0.w);
                v[4] = f2bf(x1.x); v[5] = f2bf(x1.y); v[6] = f2bf(x1.z); v[7] = f2bf(x1.w);
            }
            a[r][ks] = v;
        }
    }
    f32x4 acc[4][CF];
    #pragma unroll
    for (int r = 0; r < 4; ++r)
        #pragma unroll
        for (int cf = 0; cf < CF; ++cf)
            acc[r][cf] = (f32x4){0.f, 0.f, 0.f, 0.f};
    #pragma unroll
    for (int cf = 0; cf < CF; ++cf)
        #pragma unroll
        for (int ks = 0; ks < 4; ++ks) {
            short8 b = Bs8[(cf * 4 + ks) * 64 + lane];
            #pragma unroll
            for (int r = 0; r < 4; ++r)
                acc[r][cf] = __builtin_amdgcn_mfma_f32_16x16x32_bf16(a[r][ks], b, acc[r][cf], 0, 0, 0);
        }
    #pragma unroll
    for (int r = 0; r < 4; ++r) {
        int row0 = base + r * 16 + qr * 4;
        #pragma unroll
        for (int i = 0; i < 4; ++i) {
            int row = row0 + i;
            if (row < NNODES) {
                #pragma unroll
                for (int cf = 0; cf < CF; ++cf)
                    Y[(long)row * 128 + cf * 16 + cl] = (unsigned short)f2bf(acc[r][cf][i]);
            }
        }
    }
}

// ---------- scanA1: per-bucket exclusive scan of its 293-chunk row; emit bucket total ----------
__global__ __launch_bounds__(512) void k_scanA1(int* __restrict__ bh,
                                                int* __restrict__ bt) {
    __shared__ int s[512];
    int b = blockIdx.x;
    int t = threadIdx.x;
    int v = (t < EB) ? bh[b * EB + t] : 0;
    s[t] = v;
    __syncthreads();
    for (int off = 1; off < 512; off <<= 1) {
        int u = (t >= off) ? s[t - off] : 0;
        __syncthreads();
        s[t] += u;
        __syncthreads();
    }
    if (t < EB) bh[b * EB + t] = s[t] - v;    // exclusive within row
    if (t == EB - 1) bt[b] = s[t];            // row total (unscanned)
}

// ---------- pass A2: partition edges into dst-buckets (local bt scan, LDS cursors) ----------
__global__ __launch_bounds__(256) void k_passA2(const int* __restrict__ ei,
                                                const int* __restrict__ bh,
                                                const int* __restrict__ bt,
                                                int2* __restrict__ parted) {
    __shared__ int sc[256];
    __shared__ int cur[NBKT];
    int eb = blockIdx.x;
    int t = threadIdx.x;
    int v = (t < NBKT) ? bt[t] : 0;
    sc[t] = v;
    __syncthreads();
    for (int off = 1; off < 256; off <<= 1) {
        int u = (t >= off) ? sc[t - off] : 0;
        __syncthreads();
        sc[t] += u;
        __syncthreads();
    }
    if (t < NBKT) cur[t] = (sc[t] - v) + bh[t * EB + eb];
    __syncthreads();
    int e0 = eb * CHK;
    int e1 = min(e0 + CHK, NEDGES);
    int n4 = (e1 - e0) >> 2;
    const int4* sp = (const int4*)(ei + e0);
    const int4* dp = (const int4*)(ei + NEDGES + e0);
    for (int i = t; i < n4; i += 256) {
        int4 sv = sp[i];
        int4 dv = dp[i];
        int p0 = atomicAdd(&cur[dv.x >> 8], 1); parted[p0] = make_int2(sv.x, dv.x);
        int p1 = atomicAdd(&cur[dv.y >> 8], 1); parted[p1] = make_int2(sv.y, dv.y);
        int p2 = atomicAdd(&cur[dv.z >> 8], 1); parted[p2] = make_int2(sv.z, dv.z);
        int p3 = atomicAdd(&cur[dv.w >> 8], 1); parted[p3] = make_int2(sv.w, dv.w);
    }
}

// ---------- pass B: per-bucket count/scan/scatter -> rp, csr_src, dinv (local bt scan) ----------
__global__ __launch_bounds__(256) void k_passB(const int* __restrict__ bt,
                                               const int2* __restrict__ parted,
                                               int* __restrict__ rp,
                                               int* __restrict__ csr,
                                               float* __restrict__ dinv) {
    __shared__ int cnt2[256], cur[256], sc[256];
    int b = blockIdx.x;
    int t = threadIdx.x;
    int v = (t < NBKT) ? bt[t] : 0;
    sc[t] = v;
    __syncthreads();
    for (int o = 1; o < 256; o <<= 1) {
        int u = (t >= o) ? sc[t - o] : 0;
        __syncthreads();
        sc[t] += u;
        __syncthreads();
    }
    __shared__ int lo_sh, hi_sh;
    if (t == b) { lo_sh = sc[t] - v; hi_sh = sc[t]; }
    __syncthreads();
    int lo = lo_sh, hi = hi_sh;
    cnt2[t] = 0;
    __syncthreads();
    for (int i = lo + t; i < hi; i += 256)
        atomicAdd(&cnt2[parted[i].y & 255], 1);
    __syncthreads();
    sc[t] = cnt2[t];
    __syncthreads();
    for (int o = 1; o < 256; o <<= 1) {
        int u = (t >= o) ? sc[t - o] : 0;
        __syncthreads();
        sc[t] += u;
        __syncthreads();
    }
    int excl = sc[t] - cnt2[t];
    cur[t] = excl;
    int vtx = b * 256 + t;
    if (vtx < NNODES) {
        rp[vtx] = lo + excl;
        dinv[vtx] = rsqrtf((float)cnt2[t] + 1.0f);
    } else if (vtx == NNODES) {
        rp[vtx] = lo + excl;   // = NEDGES (all higher bins empty)
    }
    __syncthreads();
    for (int i = lo + t; i < hi; i += 256) {
        int2 e = parted[i];
        int pos = lo + atomicAdd(&cur[e.y & 255], 1);
        csr[pos] = e.x;
    }
}

// ---------- fused: gather layer-1 (per-edge dinv[src], relu+bias) -> LDS -> @W2 ----------
// W2 frags read from global (L2-hot 32KB table) -> LDS = 16KB -> 8 blocks/CU, 32 waves.
__global__ __launch_bounds__(256) void k_gather_gemm(const int* __restrict__ rp,
                                                     const int* __restrict__ csr_src,
                                                     const float* __restrict__ dinv,
                                                     const unsigned short* __restrict__ Hs,
                                                     const float* __restrict__ b1,
                                                     const unsigned short* __restrict__ Wf2,
                                                     unsigned short* __restrict__ Y) {
    __shared__ unsigned short h1[64 * 128];    // 16 KB, XOR-swizzled rows
    const int tid = threadIdx.x;
    const int lane = tid & 63;
    const int wave = tid >> 6;

    const int grp = lane >> 4;
    const int ln = lane & 15;
    const int c8 = ln * 8;
    const int base = blockIdx.x * 64;
    const uint4* Hp = (const uint4*)Hs;
    float4 bv0 = *reinterpret_cast<const float4*>(b1 + c8);
    float4 bv1 = *reinterpret_cast<const float4*>(b1 + c8 + 4);
    float bb[8] = {bv0.x, bv0.y, bv0.z, bv0.w, bv1.x, bv1.y, bv1.z, bv1.w};

    #pragma unroll
    for (int p = 0; p < 4; ++p) {
        int vloc = wave * 16 + p * 4 + grp;
        int v = base + vloc;
        uint4 o = {0u, 0u, 0u, 0u};
        if (v < NNODES) {
            float a[8] = {0, 0, 0, 0, 0, 0, 0, 0};
            float dd = dinv[v];
            fmabf8(Hp[((long)v * 128 + c8) >> 3], dd, a);   // self * dinv[v]
            int lo = rp[v], hi = rp[v + 1];
            int i = lo;
            for (; i + 4 <= hi; i += 4) {
                int s0 = csr_src[i], s1 = csr_src[i + 1];
                int s2 = csr_src[i + 2], s3 = csr_src[i + 3];
                float n0 = dinv[s0], n1 = dinv[s1], n2 = dinv[s2], n3 = dinv[s3];
                uint4 m0 = Hp[((long)s0 * 128 + c8) >> 3];
                uint4 m1 = Hp[((long)s1 * 128 + c8) >> 3];
                uint4 m2 = Hp[((long)s2 * 128 + c8) >> 3];
                uint4 m3 = Hp[((long)s3 * 128 + c8) >> 3];
                fmabf8(m0, n0, a); fmabf8(m1, n1, a);
                fmabf8(m2, n2, a); fmabf8(m3, n3, a);
            }
            for (; i < hi; ++i) {
                int s = csr_src[i];
                fmabf8(Hp[((long)s * 128 + c8) >> 3], dinv[s], a);
            }
            unsigned t8[8];
            #pragma unroll
            for (int j = 0; j < 8; ++j) {
                float y = fmaxf(fmaf(a[j], dd, bb[j]), 0.f);
                t8[j] = (unsigned short)f2bf(y);
            }
            o.x = t8[0] | (t8[1] << 16);
            o.y = t8[2] | (t8[3] << 16);
            o.z = t8[4] | (t8[5] << 16);
            o.w = t8[6] | (t8[7] << 16);
        }
        int byte = (vloc * 256 + c8 * 2) ^ ((vloc & 7) << 4);
        *reinterpret_cast<uint4*>((char*)h1 + byte) = o;
    }
    __syncthreads();

    // Phase B: rows wave*16..+15 ; A-frag: row=wave*16+cl, ch=ks*32+qr*8 ; B from global
    const int qr = lane >> 4;
    const int cl = lane & 15;
    const int arow = wave * 16 + cl;
    short8 afr[4];
    #pragma unroll
    for (int ks = 0; ks < 4; ++ks) {
        int byte = (arow * 256 + (ks * 32 + qr * 8) * 2) ^ ((arow & 7) << 4);
        afr[ks] = *reinterpret_cast<const short8*>((const char*)h1 + byte);
    }
    const short8* Bs8 = (const short8*)Wf2;
    f32x4 acc[4];
    #pragma unroll
    for (int cf = 0; cf < 4; ++cf) acc[cf] = (f32x4){0.f, 0.f, 0.f, 0.f};
    #pragma unroll
    for (int cf = 0; cf < 4; ++cf)
        #pragma unroll
        for (int ks = 0; ks < 4; ++ks)
            acc[cf] = __builtin_amdgcn_mfma_f32_16x16x32_bf16(afr[ks], Bs8[(cf * 4 + ks) * 64 + lane], acc[cf], 0, 0, 0);
    #pragma unroll
    for (int i = 0; i < 4; ++i) {
        int row = base + wave * 16 + qr * 4 + i;
        if (row < NNODES) {
            float dv = dinv[row];
            #pragma unroll
            for (int cf = 0; cf < 4; ++cf)
                Y[(long)row * 64 + cf * 16 + cl] = (unsigned short)f2bf(acc[cf][i] * dv);
        }
    }
}

// ---------- CSR gather layer 2: out[v] = dinv[v]*(Hs[v]+sum Hs[s]) + b2 (bf16) ----------
__global__ __launch_bounds__(256) void k_gather2(const int* __restrict__ rp,
                                                 const int* __restrict__ csr_src,
                                                 const float* __restrict__ dinv,
                                                 const unsigned short* __restrict__ Hs,
                                                 const float* __restrict__ bias,
                                                 unsigned short* __restrict__ out) {
    int lane = threadIdx.x & 7;          // 8 lanes/node, 8 ch each
    int grp = threadIdx.x >> 3;
    int v = blockIdx.x * 32 + grp;
    if (v >= NNODES) return;
    int c8 = lane * 8;
    float dd = dinv[v];
    float a[8] = {0, 0, 0, 0, 0, 0, 0, 0};
    const uint4* Hp = (const uint4*)Hs;
    addbf8(Hp[((long)v * 64 + c8) >> 3], a);
    int lo = rp[v], hi = rp[v + 1];
    int i = lo;
    for (; i + 4 <= hi; i += 4) {
        int s0 = csr_src[i], s1 = csr_src[i + 1], s2 = csr_src[i + 2], s3 = csr_src[i + 3];
        uint4 m0 = Hp[((long)s0 * 64 + c8) >> 3];
        uint4 m1 = Hp[((long)s1 * 64 + c8) >> 3];
        uint4 m2 = Hp[((long)s2 * 64 + c8) >> 3];
        uint4 m3 = Hp[((long)s3 * 64 + c8) >> 3];
        addbf8(m0, a); addbf8(m1, a); addbf8(m2, a); addbf8(m3, a);
    }
    for (; i < hi; ++i)
        addbf8(Hp[((long)csr_src[i] * 64 + c8) >> 3], a);
    unsigned t[8];
    #pragma unroll
    for (int j = 0; j < 8; ++j)
        t[j] = (unsigned short)f2bf(fmaf(a[j], dd, bias[c8 + j]));
    uint4 o;
    o.x = t[0] | (t[1] << 16);
    o.y = t[2] | (t[3] << 16);
    o.z = t[4] | (t[5] << 16);
    o.w = t[6] | (t[7] << 16);
    ((uint4*)out)[((long)v * 64 + c8) >> 3] = o;
}

// ---------- pool ----------
__device__ inline int lower_bound_i(const int* a, int n, int key) {
    int lo = 0, hi = n;
    while (lo < hi) {
        int mid = (lo + hi) >> 1;
        if (a[mid] < key) lo = mid + 1; else hi = mid;
    }
    return lo;
}

__global__ __launch_bounds__(256) void k_pool(const unsigned short* __restrict__ h2,
                                              const int* __restrict__ batch,
                                              float* __restrict__ out) {
    int g = blockIdx.x >> 4;
    int slice = blockIdx.x & 15;
    int lo = lower_bound_i(batch, NNODES, g);
    int hi = lower_bound_i(batch, NNODES, g + 1);
    int ch = threadIdx.x & 63;
    int part = threadIdx.x >> 6;
    float acc = 0.f;
    for (int v = lo + slice * 4 + part; v < hi; v += 64)
        acc += bf2f(h2[(long)v * 64 + ch]);
    __shared__ float red[256];
    red[threadIdx.x] = acc;
    __syncthreads();
    if (part == 0) {
        float s = red[ch] + red[64 + ch] + red[128 + ch] + red[192 + ch];
        atomicAdd(&out[g * 64 + ch], s);
    }
}

// ---------- launch ----------
extern "C" void kernel_launch(void* const* d_in, const int* in_sizes, int n_in,
                              void* d_out, int out_size, void* d_ws, size_t ws_size,
                              hipStream_t stream) {
    const float* x   = (const float*)d_in[0];
    const int* ei    = (const int*)d_in[1];
    const int* batch = (const int*)d_in[2];
    const float* W1  = (const float*)d_in[3];
    const float* b1  = (const float*)d_in[4];
    const float* W2  = (const float*)d_in[5];
    const float* b2  = (const float*)d_in[6];
    float* out = (float*)d_out;

    char* ws = (char*)d_ws;
    float* dinv = (float*)ws;                                   // 200 KB
    int*   rp   = (int*)(ws + (256 << 10));                     // 50001 ints
    int*   bh   = (int*)(ws + (512 << 10));                     // 57428 ints (230 KB)
    int*   bt   = (int*)(ws + (768 << 10));                     // 196 ints
    int*   csr  = (int*)(ws + (1u << 20));                      // 2.4 MB
    unsigned short* Wf1 = (unsigned short*)(ws + (3584u << 10));              // 32 KB
    unsigned short* Wf2 = (unsigned short*)(ws + (3584u << 10) + (32 << 10)); // 16 KB
    unsigned short* bufA = (unsigned short*)(ws + (4u << 20));                // 12.8 MB
    unsigned short* bufB = (unsigned short*)(ws + (4u << 20) + (size_t)NNODES * 128 * 2); // 6.4 MB
    int2* parted = (int2*)bufB;   // 4.8 MB; liveness disjoint from bufB (A2/B vs gg/g2)

    // init (build W frags, zero out)
    k_init0<<<16, 256, 0, stream>>>(W1, W2, Wf1, Wf2, out);

    // mega1: GEMM1 (blocks 0..195) || pass A bucket histogram (blocks 196..488)
    k_mega1<<<GEMM_BLKS + EB, 256, 0, stream>>>(x, Wf1, bufA, ei, bh);

    // per-bucket chunk scan (emits unscanned bucket totals)
    k_scanA1<<<NBKT, 512, 0, stream>>>(bh, bt);

    // partition edges by dst bucket; then per-bucket CSR build (rp, csr, dinv)
    k_passA2<<<EB, 256, 0, stream>>>(ei, bh, bt, parted);
    k_passB<<<NBKT, 256, 0, stream>>>(bt, parted, rp, csr, dinv);

    // fused gather1(+bias+relu, per-edge dinv[src]) -> @W2 -> Hs2
    k_gather_gemm<<<(NNODES + 63) / 64, 256, 0, stream>>>(rp, csr, dinv, bufA, b1, Wf2, bufB);

    // gather2 (+bias) -> bufA region
    k_gather2<<<(NNODES + 31) / 32, 256, 0, stream>>>(rp, csr, dinv, bufB, b2, bufA);

    // pool
    k_pool<<<NGRAPHS * 16, 256, 0, stream>>>(bufA, batch, out);
}